// Round 12
// baseline (94.586 us; speedup 1.0000x reference)
//
#include <hip/hip_runtime.h>
#include <math.h>

#define NDIR 5
#define E_ 16
#define W_ 3
#define D_ 128
#define P_ 256
#define B_ 4
#define ROWS 64
#define NPQ 4

typedef __attribute__((ext_vector_type(8))) short short8;
typedef __attribute__((ext_vector_type(4))) float f32x4;
typedef __attribute__((ext_vector_type(8))) float f32x8;

struct RoutesArg { int r[E_][W_]; };

// Replicates Python _cantor_coord + stable argsort route construction on host.
static RoutesArg make_routes() {
    float coords[E_];
    for (int i = 0; i < E_; ++i) {
        double x = (double)i / (double)(E_ - 1);
        if (x < 1e-6) x = 1e-6;
        if (x > 1.0 - 1e-6) x = 1.0 - 1e-6;
        double val = 0.0, factor = 0.5;
        for (int d = 0; d < 8; ++d) {
            x *= 3.0;
            int digit = (int)x;
            x -= (double)digit;
            if (digit == 2) val += factor;
            factor *= 0.5;
        }
        coords[i] = (float)val;
    }
    RoutesArg R;
    for (int i = 0; i < E_; ++i) {
        float d[E_]; int idx[E_];
        for (int j = 0; j < E_; ++j) { d[j] = fabsf(coords[j] - coords[i]); idx[j] = j; }
        for (int a = 1; a < E_; ++a) {
            int key = idx[a]; float kd = d[key];
            int c = a - 1;
            while (c >= 0 && d[idx[c]] > kd) { idx[c + 1] = idx[c]; --c; }
            idx[c + 1] = key;
        }
        int top[W_] = { idx[0], idx[1], idx[2] };
        if (top[0] > top[1]) { int t = top[0]; top[0] = top[1]; top[1] = t; }
        if (top[1] > top[2]) { int t = top[1]; top[1] = top[2]; top[2] = t; }
        if (top[0] > top[1]) { int t = top[0]; top[0] = top[1]; top[1] = t; }
        for (int w = 0; w < W_; ++w) R.r[i][w] = top[w];
    }
    return R;
}

// HW packed f32->bf16 (RNE), proven correct in Rounds 6/7 (absmax 0.0039).
static __device__ __forceinline__ unsigned int cvt_pk_bf16(float lo, float hi) {
    unsigned int r;
    asm("v_cvt_pk_bf16_f32 %0, %1, %2" : "=v"(r) : "v"(lo), "v"(hi));
    return r;
}

// By-VALUE vector in, literal indices only -> stays in registers (rule #20).
static __device__ __forceinline__ short8 pack8(f32x8 a) {
    union { unsigned int u[4]; short8 s; } cv;
    cv.u[0] = cvt_pk_bf16(a[0], a[1]);
    cv.u[1] = cvt_pk_bf16(a[2], a[3]);
    cv.u[2] = cvt_pk_bf16(a[4], a[5]);
    cv.u[3] = cvt_pk_bf16(a[6], a[7]);
    return cv.s;
}

// Block = (x, e, b, pq-tile of 64 rows); 1280 blocks, 4 waves.
// Waves split 2x2: (row-half of 32) x (f-half of 64). exp duplication x2
// (was x4 in R5), B-load duplication x2 (L1/L2-absorbed). No k-loop barriers.
// Each block emits its x's scaled contribution to a partial buffer.
template <bool ATOMIC>
__global__ __launch_bounds__(256) void cantor_partial_kernel(
    const float* __restrict__ Q, const float* __restrict__ K,
    const float* __restrict__ V, const float* __restrict__ betas,
    const float* __restrict__ temperature, const float* __restrict__ fusion,
    float* __restrict__ target, RoutesArg routes)
{
    __shared__ float s_lds[W_ * P_];   // 3 KB

    // XCD-bijective swizzle: 1280 blocks = 8 XCDs x 160
    const int orig = blockIdx.x;
    const int wg   = (orig & 7) * 160 + (orig >> 3);

    const int pq = wg & 3;
    const int b  = (wg >> 2) & 3;
    const int e  = (wg >> 4) & 15;
    const int x  = wg >> 8;

    const int tid  = threadIdx.x;
    const int lane = tid & 63;
    const int wv   = tid >> 6;
    const int l15  = lane & 15;
    const int lg   = lane >> 4;

    const int rowbase = (wv >> 1) * 32;   // wave's 32-row half
    const int f0      = (wv & 1) * 64;    // wave's 64-col half

    const float temp = fabsf(temperature[0]) + 1e-6f;

    // fusion softmax -> weight for this x
    float fwx;
    {
        float fv[NDIR], fmx = -1e30f, fsum = 0.f;
        #pragma unroll
        for (int i = 0; i < NDIR; ++i) { fv[i] = fusion[i]; fmx = fmaxf(fmx, fv[i]); }
        #pragma unroll
        for (int i = 0; i < NDIR; ++i) { fv[i] = __expf(fv[i] - fmx); fsum += fv[i]; }
        fwx = fv[x] / fsum;
    }

    int rt[W_]; float bf3[W_];
    #pragma unroll
    for (int w = 0; w < W_; ++w) {
        rt[w] = routes.r[e][w];
        float bv_ = betas[e * E_ + rt[w]];
        bf3[w] = (rt[w] == e) ? 1.0f : 1.0f / (1.0f + __expf(-bv_));
    }

    // stage s = K * beta (768 floats)
    #pragma unroll
    for (int w = 0; w < W_; ++w)
        s_lds[w * P_ + tid] =
            K[(((size_t)(x * E_ + rt[w])) * B_ + b) * P_ + tid] * bf3[w];

    // q rows this lane contributes to (A-fragment rows = l15 within 16-tile)
    const float* Qb = Q + (((size_t)(x * E_ + e)) * B_ + b) * P_ + pq * ROWS + rowbase;
    float q2[2];
    q2[0] = Qb[l15] / temp;
    q2[1] = Qb[16 + l15] / temp;

    __syncthreads();   // s_lds ready — the only barrier

    f32x4 acc[2][4];
    #pragma unroll
    for (int fr = 0; fr < 2; ++fr)
        #pragma unroll
        for (int c = 0; c < 4; ++c)
            acc[fr][c] = (f32x4){0.f, 0.f, 0.f, 0.f};
    float den[2] = {0.f, 0.f};

    #pragma unroll
    for (int w = 0; w < W_; ++w) {
        const float* __restrict__ Vw =
            V + (((size_t)(x * E_ + rt[w])) * B_ + b) * (size_t)(P_ * D_) + f0 + l15;
        const float* sb = s_lds + w * P_ + 8 * lg;
        for (int k8 = 0; k8 < 8; ++k8) {
            // ---- issue B (V) loads early (4 col-groups of the f-half) ----
            const float* vp = Vw + (size_t)(k8 * 32 + 8 * lg) * D_;
            f32x8 bv[4];
            #pragma unroll
            for (int c = 0; c < 4; ++c)
                #pragma unroll
                for (int i = 0; i < 8; ++i)
                    bv[c][i] = vp[i * D_ + c * 16];

            // ---- s octet for this lane group (broadcast reads) ----
            f32x8 sv;
            {
                const float4 s0_ = *reinterpret_cast<const float4*>(sb + k8 * 32);
                const float4 s1_ = *reinterpret_cast<const float4*>(sb + k8 * 32 + 4);
                sv[0] = s0_.x; sv[1] = s0_.y; sv[2] = s0_.z; sv[3] = s0_.w;
                sv[4] = s1_.x; sv[5] = s1_.y; sv[6] = s1_.z; sv[7] = s1_.w;
            }

            // ---- A fragments: 16 exps in registers (hides V latency) ----
            short8 af[2];
            #pragma unroll
            for (int fr = 0; fr < 2; ++fr) {
                f32x8 ev;
                #pragma unroll
                for (int i = 0; i < 8; ++i) ev[i] = __expf(q2[fr] * sv[i]);
                den[fr] += ((ev[0] + ev[1]) + (ev[2] + ev[3])) +
                           ((ev[4] + ev[5]) + (ev[6] + ev[7]));
                af[fr] = pack8(ev);
            }

            // ---- B fragments + 8 MFMAs ----
            #pragma unroll
            for (int c = 0; c < 4; ++c) {
                const short8 bf8 = pack8(bv[c]);
                acc[0][c] = __builtin_amdgcn_mfma_f32_16x16x32_bf16(
                    af[0], bf8, acc[0][c], 0, 0, 0);
                acc[1][c] = __builtin_amdgcn_mfma_f32_16x16x32_bf16(
                    af[1], bf8, acc[1][c], 0, 0, 0);
            }
        }
    }

    // ---- full-row denominators: sum across the 4 lane-groups ----
    #pragma unroll
    for (int fr = 0; fr < 2; ++fr) {
        den[fr] += __shfl_xor(den[fr], 16);
        den[fr] += __shfl_xor(den[fr], 32);
    }

    // ---- scale + write ----
    const size_t obase = ((((size_t)b * E_ + e) * NPQ) + pq) * (ROWS * D_);
    float* __restrict__ tgt = ATOMIC
        ? target
        : target + (size_t)x * ((size_t)B_ * E_ * NPQ * ROWS * D_);

    #pragma unroll
    for (int fr = 0; fr < 2; ++fr) {
        #pragma unroll
        for (int r = 0; r < 4; ++r) {
            const float dr = __shfl(den[fr], 4 * lg + r);   // den of row fr*16+4*lg+r
            const float sc = fwx / dr;
            const int row = rowbase + fr * 16 + 4 * lg + r;
            float* op = tgt + obase + (size_t)row * D_ + f0;
            #pragma unroll
            for (int c = 0; c < 4; ++c) {
                const float v = sc * acc[fr][c][r];
                if (ATOMIC) atomicAdd(op + c * 16 + l15, v);
                else        op[c * 16 + l15] = v;
            }
        }
    }
}

__global__ __launch_bounds__(256) void reduce5_kernel(
    const float* __restrict__ part, float* __restrict__ out)
{
    const size_t i = (size_t)blockIdx.x * 256 + threadIdx.x;   // float4 index
    const float4* __restrict__ p = reinterpret_cast<const float4*>(part);
    float4 a = p[i];
    #pragma unroll
    for (int x = 1; x < NDIR; ++x) {
        float4 t = p[(size_t)x * 524288 + i];
        a.x += t.x; a.y += t.y; a.z += t.z; a.w += t.w;
    }
    reinterpret_cast<float4*>(out)[i] = a;
}

extern "C" void kernel_launch(void* const* d_in, const int* in_sizes, int n_in,
                              void* d_out, int out_size, void* d_ws, size_t ws_size,
                              hipStream_t stream) {
    (void)in_sizes; (void)n_in;
    RoutesArg R = make_routes();
    const float* Q     = (const float*)d_in[0];
    const float* K     = (const float*)d_in[1];
    const float* V     = (const float*)d_in[2];
    const float* betas = (const float*)d_in[3];
    const float* tempr = (const float*)d_in[4];
    const float* fuse  = (const float*)d_in[5];
    float* out = (float*)d_out;

    const size_t partial_bytes = (size_t)NDIR * B_ * E_ * NPQ * ROWS * D_ * 4;  // ~42 MB
    dim3 grid(NDIR * E_ * B_ * NPQ);   // 1280
    dim3 block(256);

    if (ws_size >= partial_bytes) {
        float* part = (float*)d_ws;
        hipLaunchKernelGGL((cantor_partial_kernel<false>), grid, block, 0, stream,
                           Q, K, V, betas, tempr, fuse, part, R);
        hipLaunchKernelGGL(reduce5_kernel, dim3(2048), block, 0, stream,
                           part, out);
    } else {
        (void)hipMemsetAsync(d_out, 0, (size_t)out_size * 4, stream);
        hipLaunchKernelGGL((cantor_partial_kernel<true>), grid, block, 0, stream,
                           Q, K, V, betas, tempr, fuse, out, R);
    }
}

// Round 13
// 64.877 us; speedup vs baseline: 1.4579x; 1.4579x over previous
//
#include <hip/hip_runtime.h>
#include <math.h>

#define NDIR 5
#define E_ 16
#define W_ 3
#define D_ 128
#define P_ 256
#define B_ 4
#define ROWS 64
#define NPQ 4
#define STEPS 24   // W_ * 8 k8-steps

typedef __attribute__((ext_vector_type(8))) short short8;
typedef __attribute__((ext_vector_type(4))) float f32x4;
typedef __attribute__((ext_vector_type(8))) float f32x8;

struct RoutesArg { int r[E_][W_]; };

// Replicates Python _cantor_coord + stable argsort route construction on host.
static RoutesArg make_routes() {
    float coords[E_];
    for (int i = 0; i < E_; ++i) {
        double x = (double)i / (double)(E_ - 1);
        if (x < 1e-6) x = 1e-6;
        if (x > 1.0 - 1e-6) x = 1.0 - 1e-6;
        double val = 0.0, factor = 0.5;
        for (int d = 0; d < 8; ++d) {
            x *= 3.0;
            int digit = (int)x;
            x -= (double)digit;
            if (digit == 2) val += factor;
            factor *= 0.5;
        }
        coords[i] = (float)val;
    }
    RoutesArg R;
    for (int i = 0; i < E_; ++i) {
        float d[E_]; int idx[E_];
        for (int j = 0; j < E_; ++j) { d[j] = fabsf(coords[j] - coords[i]); idx[j] = j; }
        for (int a = 1; a < E_; ++a) {
            int key = idx[a]; float kd = d[key];
            int c = a - 1;
            while (c >= 0 && d[idx[c]] > kd) { idx[c + 1] = idx[c]; --c; }
            idx[c + 1] = key;
        }
        int top[W_] = { idx[0], idx[1], idx[2] };
        if (top[0] > top[1]) { int t = top[0]; top[0] = top[1]; top[1] = t; }
        if (top[1] > top[2]) { int t = top[1]; top[1] = top[2]; top[2] = t; }
        if (top[0] > top[1]) { int t = top[0]; top[0] = top[1]; top[1] = t; }
        for (int w = 0; w < W_; ++w) R.r[i][w] = top[w];
    }
    return R;
}

// HW packed f32->bf16 (RNE), proven correct in Rounds 6/7/12 (absmax 0.0039).
static __device__ __forceinline__ unsigned int cvt_pk_bf16(float lo, float hi) {
    unsigned int r;
    asm("v_cvt_pk_bf16_f32 %0, %1, %2" : "=v"(r) : "v"(lo), "v"(hi));
    return r;
}

// By-VALUE vector in, literal indices only -> stays in registers (rule #20).
static __device__ __forceinline__ short8 pack8(f32x8 a) {
    union { unsigned int u[4]; short8 s; } cv;
    cv.u[0] = cvt_pk_bf16(a[0], a[1]);
    cv.u[1] = cvt_pk_bf16(a[2], a[3]);
    cv.u[2] = cvt_pk_bf16(a[4], a[5]);
    cv.u[3] = cvt_pk_bf16(a[6], a[7]);
    return cv.s;
}

// Block = (x, e, b, pq-tile of 64 rows); 1280 blocks, 4 waves, 2x2 wave split
// (32 rows x 64 cols each). Explicit half-step software pipeline on the V
// loads: col-pair {0,1} computes while {2,3} and next step's {0,1} are in
// flight -> V L2 latency hidden under exp/pack VALU work. No k-loop barriers.
template <bool ATOMIC>
__global__ __launch_bounds__(256, 4) void cantor_partial_kernel(
    const float* __restrict__ Q, const float* __restrict__ K,
    const float* __restrict__ V, const float* __restrict__ betas,
    const float* __restrict__ temperature, const float* __restrict__ fusion,
    float* __restrict__ target, RoutesArg routes)
{
    __shared__ float s_lds[W_ * P_];   // 3 KB

    // XCD-bijective swizzle: 1280 blocks = 8 XCDs x 160
    const int orig = blockIdx.x;
    const int wg   = (orig & 7) * 160 + (orig >> 3);

    const int pq = wg & 3;
    const int b  = (wg >> 2) & 3;
    const int e  = (wg >> 4) & 15;
    const int x  = wg >> 8;

    const int tid  = threadIdx.x;
    const int lane = tid & 63;
    const int wv   = tid >> 6;
    const int l15  = lane & 15;
    const int lg   = lane >> 4;

    const int rowbase = (wv >> 1) * 32;   // wave's 32-row half
    const int f0      = (wv & 1) * 64;    // wave's 64-col half

    const float temp = fabsf(temperature[0]) + 1e-6f;

    // fusion softmax -> weight for this x
    float fwx;
    {
        float fv[NDIR], fmx = -1e30f, fsum = 0.f;
        #pragma unroll
        for (int i = 0; i < NDIR; ++i) { fv[i] = fusion[i]; fmx = fmaxf(fmx, fv[i]); }
        #pragma unroll
        for (int i = 0; i < NDIR; ++i) { fv[i] = __expf(fv[i] - fmx); fsum += fv[i]; }
        fwx = fv[x] / fsum;
    }

    int rt[W_]; float bf3[W_];
    #pragma unroll
    for (int w = 0; w < W_; ++w) {
        rt[w] = routes.r[e][w];
        float bv_ = betas[e * E_ + rt[w]];
        bf3[w] = (rt[w] == e) ? 1.0f : 1.0f / (1.0f + __expf(-bv_));
    }

    // stage s = K * beta (768 floats)
    #pragma unroll
    for (int w = 0; w < W_; ++w)
        s_lds[w * P_ + tid] =
            K[(((size_t)(x * E_ + rt[w])) * B_ + b) * P_ + tid] * bf3[w];

    // q rows this lane contributes to
    const float* Qb = Q + (((size_t)(x * E_ + e)) * B_ + b) * P_ + pq * ROWS + rowbase;
    float q2[2];
    q2[0] = Qb[l15] / temp;
    q2[1] = Qb[16 + l15] / temp;

    // per-route base pointers (named values -> 3-way select, no scratch)
    const float* vb0 = V + (((size_t)(x * E_ + rt[0])) * B_ + b) * (size_t)(P_ * D_) + f0 + l15;
    const float* vb1 = V + (((size_t)(x * E_ + rt[1])) * B_ + b) * (size_t)(P_ * D_) + f0 + l15;
    const float* vb2 = V + (((size_t)(x * E_ + rt[2])) * B_ + b) * (size_t)(P_ * D_) + f0 + l15;
    const float* sp0 = s_lds + 0 * P_ + 8 * lg;
    const float* sp1 = s_lds + 1 * P_ + 8 * lg;
    const float* sp2 = s_lds + 2 * P_ + 8 * lg;

    __syncthreads();   // s_lds ready — the only barrier

    f32x4 acc[2][4];
    #pragma unroll
    for (int fr = 0; fr < 2; ++fr)
        #pragma unroll
        for (int c = 0; c < 4; ++c)
            acc[fr][c] = (f32x4){0.f, 0.f, 0.f, 0.f};
    float den[2] = {0.f, 0.f};

    // ---- half-step pipelined k-loop ----
    // hA/hB: named double buffers (2 col-groups each), literal indices only.
    f32x8 hA0, hA1, hB0, hB1;

    // vp(g) = row base for step g; cols hA: +0,+16 ; hB: +32,+48
    #define VPTR(g) ((((g) < 8) ? vb0 : (((g) < 16) ? vb1 : vb2)) \
                     + (size_t)((((g) & 7) * 32) + 8 * lg) * D_)
    #define SPTR(g) ((((g) < 8) ? sp0 : (((g) < 16) ? sp1 : sp2)) + (((g) & 7) * 32))

    #define LOADH(d0, d1, vp_, cbase) do {                    \
        _Pragma("unroll")                                     \
        for (int i_ = 0; i_ < 8; ++i_) {                      \
            d0[i_] = (vp_)[i_ * D_ + (cbase) * 16];           \
            d1[i_] = (vp_)[i_ * D_ + ((cbase) + 1) * 16];     \
        }                                                     \
    } while (0)

    {
        const float* vp0 = VPTR(0);
        LOADH(hA0, hA1, vp0, 0);   // prologue: step 0, cols {0,1}
    }

    for (int g = 0; g < STEPS; ++g) {
        const float* vpg = VPTR(g);
        // issue cols {2,3} of this step
        LOADH(hB0, hB1, vpg, 2);

        // s octet (LDS broadcast) + A fragments: 16 exps
        const float* sp = SPTR(g);
        f32x8 sv;
        {
            const float4 s0_ = *reinterpret_cast<const float4*>(sp);
            const float4 s1_ = *reinterpret_cast<const float4*>(sp + 4);
            sv[0] = s0_.x; sv[1] = s0_.y; sv[2] = s0_.z; sv[3] = s0_.w;
            sv[4] = s1_.x; sv[5] = s1_.y; sv[6] = s1_.z; sv[7] = s1_.w;
        }
        short8 af[2];
        #pragma unroll
        for (int fr = 0; fr < 2; ++fr) {
            f32x8 ev;
            #pragma unroll
            for (int i = 0; i < 8; ++i) ev[i] = __expf(q2[fr] * sv[i]);
            den[fr] += ((ev[0] + ev[1]) + (ev[2] + ev[3])) +
                       ((ev[4] + ev[5]) + (ev[6] + ev[7]));
            af[fr] = pack8(ev);
        }

        // consume hA (cols {0,1}; loads issued one compute-phase ago)
        {
            const short8 b0 = pack8(hA0);
            const short8 b1 = pack8(hA1);
            acc[0][0] = __builtin_amdgcn_mfma_f32_16x16x32_bf16(af[0], b0, acc[0][0], 0, 0, 0);
            acc[1][0] = __builtin_amdgcn_mfma_f32_16x16x32_bf16(af[1], b0, acc[1][0], 0, 0, 0);
            acc[0][1] = __builtin_amdgcn_mfma_f32_16x16x32_bf16(af[0], b1, acc[0][1], 0, 0, 0);
            acc[1][1] = __builtin_amdgcn_mfma_f32_16x16x32_bf16(af[1], b1, acc[1][1], 0, 0, 0);
        }

        // issue next step's cols {0,1}
        if (g + 1 < STEPS) {
            const float* vpn = VPTR(g + 1);
            LOADH(hA0, hA1, vpn, 0);
        }

        // consume hB (cols {2,3})
        {
            const short8 b2 = pack8(hB0);
            const short8 b3 = pack8(hB1);
            acc[0][2] = __builtin_amdgcn_mfma_f32_16x16x32_bf16(af[0], b2, acc[0][2], 0, 0, 0);
            acc[1][2] = __builtin_amdgcn_mfma_f32_16x16x32_bf16(af[1], b2, acc[1][2], 0, 0, 0);
            acc[0][3] = __builtin_amdgcn_mfma_f32_16x16x32_bf16(af[0], b3, acc[0][3], 0, 0, 0);
            acc[1][3] = __builtin_amdgcn_mfma_f32_16x16x32_bf16(af[1], b3, acc[1][3], 0, 0, 0);
        }
    }
    #undef VPTR
    #undef SPTR
    #undef LOADH

    // ---- full-row denominators: sum across the 4 lane-groups ----
    #pragma unroll
    for (int fr = 0; fr < 2; ++fr) {
        den[fr] += __shfl_xor(den[fr], 16);
        den[fr] += __shfl_xor(den[fr], 32);
    }

    // ---- scale + write ----
    const size_t obase = ((((size_t)b * E_ + e) * NPQ) + pq) * (ROWS * D_);
    float* __restrict__ tgt = ATOMIC
        ? target
        : target + (size_t)x * ((size_t)B_ * E_ * NPQ * ROWS * D_);

    #pragma unroll
    for (int fr = 0; fr < 2; ++fr) {
        #pragma unroll
        for (int r = 0; r < 4; ++r) {
            const float dr = __shfl(den[fr], 4 * lg + r);   // den of row fr*16+4*lg+r
            const float sc = fwx / dr;
            const int row = rowbase + fr * 16 + 4 * lg + r;
            float* op = tgt + obase + (size_t)row * D_ + f0;
            #pragma unroll
            for (int c = 0; c < 4; ++c) {
                const float v = sc * acc[fr][c][r];
                if (ATOMIC) atomicAdd(op + c * 16 + l15, v);
                else        op[c * 16 + l15] = v;
            }
        }
    }
}

__global__ __launch_bounds__(256) void reduce5_kernel(
    const float* __restrict__ part, float* __restrict__ out)
{
    const size_t i = (size_t)blockIdx.x * 256 + threadIdx.x;   // float4 index
    const float4* __restrict__ p = reinterpret_cast<const float4*>(part);
    float4 a = p[i];
    #pragma unroll
    for (int x = 1; x < NDIR; ++x) {
        float4 t = p[(size_t)x * 524288 + i];
        a.x += t.x; a.y += t.y; a.z += t.z; a.w += t.w;
    }
    reinterpret_cast<float4*>(out)[i] = a;
}

extern "C" void kernel_launch(void* const* d_in, const int* in_sizes, int n_in,
                              void* d_out, int out_size, void* d_ws, size_t ws_size,
                              hipStream_t stream) {
    (void)in_sizes; (void)n_in;
    RoutesArg R = make_routes();
    const float* Q     = (const float*)d_in[0];
    const float* K     = (const float*)d_in[1];
    const float* V     = (const float*)d_in[2];
    const float* betas = (const float*)d_in[3];
    const float* tempr = (const float*)d_in[4];
    const float* fuse  = (const float*)d_in[5];
    float* out = (float*)d_out;

    const size_t partial_bytes = (size_t)NDIR * B_ * E_ * NPQ * ROWS * D_ * 4;  // ~42 MB
    dim3 grid(NDIR * E_ * B_ * NPQ);   // 1280
    dim3 block(256);

    if (ws_size >= partial_bytes) {
        float* part = (float*)d_ws;
        hipLaunchKernelGGL((cantor_partial_kernel<false>), grid, block, 0, stream,
                           Q, K, V, betas, tempr, fuse, part, R);
        hipLaunchKernelGGL(reduce5_kernel, dim3(2048), block, 0, stream,
                           part, out);
    } else {
        (void)hipMemsetAsync(d_out, 0, (size_t)out_size * 4, stream);
        hipLaunchKernelGGL((cantor_partial_kernel<true>), grid, block, 0, stream,
                           Q, K, V, betas, tempr, fuse, out, R);
    }
}